// Round 10
// baseline (74.257 us; speedup 1.0000x reference)
//
#include <hip/hip_runtime.h>
#include <hip/hip_bf16.h>
#include <math.h>

// Problem constants
#define BB 8
#define SS 2048
#define DD 768
#define NPOS 512
#define TC 64                 // ctx chunks (32 rows each) -> 512 blocks
#define DSPLIT 24             // d-splits for q@W
#define DSL (DD / DSPLIT)     // 32
#define ETOT (DD + NPOS)      // 1280
#define SCALE 0.036084391824351615f   // 1/sqrt(768)

// Workspace layout (float offsets, 16B-aligned)
#define WS_LOGITS 0        // 16384
#define WS_CTX    16384    // 6144 (atomic-accumulated; zeroed in k_prep)
#define WS_PWS    22528    // DSPLIT*BB*ETOT = 245760 (qk/lint partials)
#define WS_PWQ    268288   // DSPLIT*BB = 192 (qbk partials)
// total 268480 floats = 1.07 MB

__device__ __forceinline__ float wave_sum(float v) {
    #pragma unroll
    for (int off = 32; off > 0; off >>= 1) v += __shfl_xor(v, off, 64);
    return v;
}

// Fused prep: grid (5, DSPLIT), 256 thr. Each block loads x0 (8 rows) into LDS,
// computes its 32-dim q-slice thread-per-output (256 = 8b x 32d, deterministic,
// ILP-2 split), then the batch-shared partial q@[Wk|pos_emb] for its e-range.
// part==0 blocks also write qbk partials. Zeros ctx.
__global__ __launch_bounds__(256) void k_prep(const float* __restrict__ x,
        const float* __restrict__ Wq, const float* __restrict__ bq,
        const float* __restrict__ Wk, const float* __restrict__ bk,
        const float* __restrict__ pos_emb, float* __restrict__ ws) {
    const int part = blockIdx.x, ds = blockIdx.y, tid = threadIdx.x;
    float* ctx = ws + WS_CTX;
    float* pws = ws + WS_PWS;
    float* pwq = ws + WS_PWQ;

    __shared__ float x0s[BB][DD];   // 24 KB
    __shared__ float qs[BB][DSL];

    int gt = (blockIdx.y * 5 + blockIdx.x) * 256 + tid;
    if (gt < BB * DD) ctx[gt] = 0.f;

    // load x[b,0,:] for all 8 batches (1536 float4, 6 per thread)
    for (int i = tid; i < BB * (DD / 4); i += 256) {
        int b = i / 192, c = i % 192;
        ((float4*)x0s[b])[c] = *((const float4*)(x + (size_t)b * SS * DD) + c);
    }
    __syncthreads();

    // Phase A: q-slice, thread-per-output. b = tid>>5 (wave spans 2 b's ->
    // LDS broadcast x2, conflict-free), dl = tid&31.
    {
        int b = tid >> 5, dl = tid & 31;
        int d = ds * DSL + dl;
        const float4* w4 = (const float4*)(Wq + (size_t)d * DD);
        const float4* x4 = (const float4*)x0s[b];
        float a0 = 0.f, a1 = 0.f;
        #pragma unroll 8
        for (int k = 0; k < 96; ++k) {
            float4 w = w4[k], a = x4[k];
            a0 += a.x * w.x + a.y * w.y + a.z * w.z + a.w * w.w;
        }
        #pragma unroll 8
        for (int k = 96; k < 192; ++k) {
            float4 w = w4[k], a = x4[k];
            a1 += a.x * w.x + a.y * w.y + a.z * w.z + a.w * w.w;
        }
        qs[b][dl] = a0 + a1 + bq[d];
    }
    __syncthreads();

    // qbk partials (deterministic per-slice serial)
    if (part == 0 && tid < BB) {
        float p = 0.f;
        #pragma unroll
        for (int d = 0; d < DSL; ++d) p += qs[tid][d] * bk[ds * DSL + d];
        pwq[ds * BB + tid] = p;
    }

    // Phase B: partial q @ [Wk | pos_emb] for this block's e-range
    const float* Wsrc; int stride, eg;
    if (part < 3) { Wsrc = Wk; stride = DD; eg = part * 256 + tid; }
    else { Wsrc = pos_emb; stride = NPOS; eg = DD + (part - 3) * 256 + tid; }
    int e = (part < 3) ? eg : eg - DD;
    const float* col = Wsrc + (size_t)(ds * DSL) * stride + e;
    float acc[BB];
    #pragma unroll
    for (int b = 0; b < BB; ++b) acc[b] = 0.f;
    #pragma unroll 4
    for (int d = 0; d < DSL; ++d) {
        float w = col[(size_t)d * stride];
        #pragma unroll
        for (int b = 0; b < BB; ++b) acc[b] += qs[b][d] * w;
    }
    #pragma unroll
    for (int b = 0; b < BB; ++b)
        pws[((size_t)ds * BB + b) * ETOT + eg] = acc[b];
}

// logits: grid (128, BB) = 1024 blocks, 256 thr (4 waves), 4 rows per wave.
// Prologue: reduce pws->qk (redundant per block, deterministic) into
// component-split LDS; reduce pwq->qbk. Body: wave-per-row dot (50 MB stream).
__global__ __launch_bounds__(256) void k_logits(const float* __restrict__ x,
        const float* __restrict__ pws, const float* __restrict__ pwq,
        const int* __restrict__ mask, float* __restrict__ logits) {
    const int chunk = blockIdx.x, b = blockIdx.y, tid = threadIdx.x;
    const int lane = tid & 63, wid = tid >> 6;
    __shared__ float sq[4][192];    // component-split qk[b,:] (conflict-free)
    __shared__ float sqbk;
    for (int e = tid; e < DD; e += 256) {
        float acc = 0.f;
        #pragma unroll 4
        for (int ds = 0; ds < DSPLIT; ++ds)
            acc += pws[((size_t)ds * BB + b) * ETOT + e];
        sq[e & 3][e >> 2] = acc;
    }
    if (wid == 3) {
        float p = (lane < DSPLIT) ? pwq[lane * BB + b] : 0.f;
        p = wave_sum(p);
        if (lane == 0) sqbk = p;
    }
    __syncthreads();
    #pragma unroll
    for (int r = 0; r < 4; ++r) {
        int trow = chunk * 16 + wid * 4 + r;
        const float4* xr = (const float4*)(x + ((size_t)b * SS + trow) * DD);
        float acc = 0.f;
        #pragma unroll
        for (int j = 0; j < 3; ++j) {
            int i = lane + 64 * j;
            float4 a = xr[i];
            acc += a.x * sq[0][i] + a.y * sq[1][i] + a.z * sq[2][i] + a.w * sq[3][i];
        }
        acc = wave_sum(acc);
        if (lane == 0) {
            int o = b * SS + trow;
            logits[o] = mask[o] ? (acc + sqbk) * SCALE : -INFINITY;
        }
    }
}

// Fused scan + ctx: grid (TC, BB) = (64, 8), 256 thr. Prologue reduces
// pws->lint (deterministic). Each block runs the proven scan (identical attn
// everywhere), then accumulates its 32-row x chunk into ctx (atomic, linear).
__global__ __launch_bounds__(256) void k_ctxscan(const float* __restrict__ x,
        const float* __restrict__ logits, const float* __restrict__ pws,
        float* __restrict__ ctx) {
    const int tc = blockIdx.x, b = blockIdx.y, tid = threadIdx.x;
    __shared__ float lg[SS];
    __shared__ float li[NPOS];
    __shared__ float sa[256], sb[256];
    for (int i = tid; i < SS; i += 256) lg[i] = logits[b * SS + i];
    for (int e = tid; e < NPOS; e += 256) {
        float acc = 0.f;
        #pragma unroll 4
        for (int ds = 0; ds < DSPLIT; ++ds)
            acc += pws[((size_t)ds * BB + b) * ETOT + DD + e];
        li[e] = acc;
    }
    __syncthreads();
    int base = tid * 8;
    float loc[8];
    float run = 0.f;
    #pragma unroll
    for (int k = 7; k >= 0; --k) {          // suffix sum within own chunk
        float v = lg[base + k];
        float gk = 1.f / (1.f + expf(-v));  // sigmoid; -inf -> 0
        run += gk;
        loc[k] = run;
    }
    sa[tid] = run;
    __syncthreads();
    // Hillis-Steele inclusive SUFFIX scan over 256 chunk totals (ping-pong)
    float* src = sa; float* dst = sb;
    for (int off = 1; off < 256; off <<= 1) {
        float v = src[tid];
        if (tid + off < 256) v += src[tid + off];
        dst[tid] = v;
        __syncthreads();
        float* t_ = src; src = dst; dst = t_;
    }
    float st = (tid < 255) ? src[tid + 1] : 0.f;
    float adj[8];
    float m = -INFINITY;
    #pragma unroll
    for (int k = 0; k < 8; ++k) {
        float val = lg[base + k];
        float nv;
        if (val == -INFINITY) {
            nv = val;
        } else {
            float p = fminf(loc[k] + st, (float)(NPOS - 1));
            float pf = floorf(p);
            float wt = p - pf;
            int fi = (int)pf;
            int ci = (int)ceilf(p);
            nv = val + li[ci] * wt + li[fi] * (1.f - wt);
        }
        adj[k] = nv;
        m = fmaxf(m, nv);
    }
    __syncthreads();            // scan LDS reads done; safe to reuse sa/sb
    sa[tid] = m;
    __syncthreads();
    for (int s2 = 128; s2 > 0; s2 >>= 1) {
        if (tid < s2) sa[tid] = fmaxf(sa[tid], sa[tid + s2]);
        __syncthreads();
    }
    float bm = sa[0];
    __syncthreads();
    float sum = 0.f;
    #pragma unroll
    for (int k = 0; k < 8; ++k) { adj[k] = expf(adj[k] - bm); sum += adj[k]; }
    sa[tid] = sum;
    __syncthreads();
    for (int s2 = 128; s2 > 0; s2 >>= 1) {
        if (tid < s2) sa[tid] += sa[tid + s2];
        __syncthreads();
    }
    float inv = 1.f / sa[0];
    #pragma unroll
    for (int k = 0; k < 8; ++k) lg[base + k] = adj[k] * inv;   // attn into lg
    __syncthreads();
    // weighted x-row sum for this block's 32-row chunk
    if (tid < 192) {
        const int TPC = SS / TC;  // 32
        float4 acc = make_float4(0.f, 0.f, 0.f, 0.f);
        const float4* xr = (const float4*)(x + ((size_t)b * SS + (size_t)tc * TPC) * DD);
        const float* at = lg + tc * TPC;
        for (int i = 0; i < TPC; ++i) {
            float a = at[i];
            float4 xv = xr[(size_t)i * 192 + tid];
            acc.x += a * xv.x; acc.y += a * xv.y; acc.z += a * xv.z; acc.w += a * xv.w;
        }
        float* dstp = ctx + b * DD + tid * 4;
        atomicAdd(dstp + 0, acc.x);
        atomicAdd(dstp + 1, acc.y);
        atomicAdd(dstp + 2, acc.z);
        atomicAdd(dstp + 3, acc.w);
    }
}

// out[b,d] = ctx[b,:].Wv[d,:] + bv[d]; wave per output.
__global__ __launch_bounds__(256) void k_out(const float* __restrict__ ctx,
        const float* __restrict__ Wv, const float* __restrict__ bv,
        float* __restrict__ out) {
    int gw = (blockIdx.x * 256 + threadIdx.x) >> 6;
    int lane = threadIdx.x & 63;
    if (gw >= BB * DD) return;
    int b = gw / DD, d = gw % DD;
    const float4* vr = (const float4*)(ctx + (size_t)b * DD);
    const float4* wr = (const float4*)(Wv + (size_t)d * DD);
    float acc = 0.f;
    #pragma unroll
    for (int j = 0; j < 3; ++j) {
        float4 a = vr[lane + 64 * j];
        float4 w = wr[lane + 64 * j];
        acc += a.x * w.x + a.y * w.y + a.z * w.z + a.w * w.w;
    }
    acc = wave_sum(acc);
    if (lane == 0) out[gw] = acc + bv[d];
}

extern "C" void kernel_launch(void* const* d_in, const int* in_sizes, int n_in,
                              void* d_out, int out_size, void* d_ws, size_t ws_size,
                              hipStream_t stream) {
    const float* x       = (const float*)d_in[0];  // [B,S,D]
    const int*   mask    = (const int*)  d_in[1];  // [B,S]
    const float* Wq      = (const float*)d_in[2];
    const float* bq      = (const float*)d_in[3];
    const float* Wk      = (const float*)d_in[4];
    const float* bk      = (const float*)d_in[5];
    const float* Wv      = (const float*)d_in[6];
    const float* bv      = (const float*)d_in[7];
    const float* pos_emb = (const float*)d_in[8];  // [D,NPOS]
    float* out = (float*)d_out;                    // [B,D]
    float* ws  = (float*)d_ws;

    float* logits = ws + WS_LOGITS;
    float* ctx    = ws + WS_CTX;
    float* pws    = ws + WS_PWS;
    float* pwq    = ws + WS_PWQ;

    // 1. fused prep: q-slices (thread-per-output) -> qk/lint/qbk partials; zero ctx
    k_prep<<<dim3(5, DSPLIT), dim3(256), 0, stream>>>(x, Wq, bq, Wk, bk, pos_emb, ws);
    // 2. logits (pass 1 over x, 50 MB; qk reduced in prologue; 1024 blocks)
    k_logits<<<dim3(128, BB), dim3(256), 0, stream>>>(x, pws, pwq, mask, logits);
    // 3. fused scan + ctx (pass 2 over x; lint reduced in prologue; 512 blocks)
    k_ctxscan<<<dim3(TC, BB), dim3(256), 0, stream>>>(x, logits, pws, ctx);
    // 4. out = ctx @ Wv.T + bv
    k_out<<<dim3((BB * DD) / 4), dim3(256), 0, stream>>>(ctx, Wv, bv, out);
}

// Round 11
// 51.182 us; speedup vs baseline: 1.4508x; 1.4508x over previous
//
#include <hip/hip_runtime.h>
#include <hip/hip_bf16.h>
#include <math.h>

// Problem constants
#define BB 8
#define SS 2048
#define DD 768
#define NPOS 512
#define TC 64                 // ctx chunks (32 rows each) -> 512 blocks
#define DSPLIT 16             // d-splits for q@W (R2-proven)
#define DSL (DD / DSPLIT)     // 48
#define ETOT (DD + NPOS)      // 1280
#define SCALE 0.036084391824351615f   // 1/sqrt(768)

// Workspace layout (float offsets, 16B-aligned)
#define WS_LOGITS 0        // 16384
#define WS_CTX    16384    // 6144 (atomic-accumulated; zeroed in k_q)
#define WS_Q      22528    // 6144
#define WS_QK     28672    // 6144
#define WS_LI     34816    // 4096
#define WS_QBK    38912    // 16
#define WS_PWS    38928    // DSPLIT*BB*ETOT = 163840 (qk/lint partials)
// total 202768 floats = 811 KB

__device__ __forceinline__ float wave_sum(float v) {
    #pragma unroll
    for (int off = 32; off > 0; off >>= 1) v += __shfl_xor(v, off, 64);
    return v;
}

// q[b,d] = x[b,0,:].Wq[d,:] + bq[d]; wave per output (1536 blocks); zeros ctx.
__global__ __launch_bounds__(256) void k_q(const float* __restrict__ x,
        const float* __restrict__ Wq, const float* __restrict__ bq,
        float* __restrict__ q, float* __restrict__ ctx) {
    int zi = blockIdx.x * 256 + threadIdx.x;
    if (zi < BB * DD) ctx[zi] = 0.f;
    int gw = zi >> 6;
    int lane = threadIdx.x & 63;
    if (gw >= BB * DD) return;
    int b = gw / DD, d = gw % DD;
    const float4* vr = (const float4*)(x + (size_t)b * SS * DD);
    const float4* wr = (const float4*)(Wq + (size_t)d * DD);
    float acc = 0.f;
    #pragma unroll
    for (int j = 0; j < 3; ++j) {
        float4 a = vr[lane + 64 * j];
        float4 w = wr[lane + 64 * j];
        acc += a.x * w.x + a.y * w.y + a.z * w.z + a.w * w.w;
    }
    acc = wave_sum(acc);
    if (lane == 0) q[gw] = acc + bq[d];
}

// Partial q@[Wk | pos_emb] -> pws (deterministic float, R2-proven shape).
// grid (5, DSPLIT): x 0..2 -> Wk e-chunks of 256; 3..4 -> pos_emb chunks.
// Block (0,0) also computes qbk[b] = q[b,:].bk (wave-deterministic).
__global__ __launch_bounds__(256) void k_qkw(const float* __restrict__ q,
        const float* __restrict__ Wk, const float* __restrict__ bk,
        const float* __restrict__ pos_emb,
        float* __restrict__ pws, float* __restrict__ qbk) {
    int part = blockIdx.x, ds = blockIdx.y, tid = threadIdx.x;
    __shared__ float qs[BB][DSL];
    for (int i = tid; i < BB * DSL; i += 256) {
        int b = i / DSL, d = i % DSL;
        qs[b][d] = q[b * DD + ds * DSL + d];
    }
    __syncthreads();
    const float* Wsrc; int stride, eg;
    if (part < 3) { Wsrc = Wk; stride = DD; eg = part * 256 + tid; }
    else { Wsrc = pos_emb; stride = NPOS; eg = DD + (part - 3) * 256 + tid; }
    int e = (part < 3) ? eg : eg - DD;
    const float* col = Wsrc + (size_t)(ds * DSL) * stride + e;
    float acc[BB];
    #pragma unroll
    for (int b = 0; b < BB; ++b) acc[b] = 0.f;
    #pragma unroll 4
    for (int d = 0; d < DSL; ++d) {
        float w = col[(size_t)d * stride];
        #pragma unroll
        for (int b = 0; b < BB; ++b) acc[b] += qs[b][d] * w;
    }
    #pragma unroll
    for (int b = 0; b < BB; ++b)
        pws[((size_t)ds * BB + b) * ETOT + eg] = acc[b];
    // qbk: one block, 4 waves x 2 batches each (deterministic wave_sum)
    if (part == 0 && ds == 0) {
        int w = tid >> 6, lane = tid & 63;
        #pragma unroll
        for (int r = 0; r < 2; ++r) {
            int b = w + 4 * r;
            float p = 0.f;
            #pragma unroll
            for (int j = 0; j < 12; ++j)
                p += q[b * DD + lane + 64 * j] * bk[lane + 64 * j];
            p = wave_sum(p);
            if (lane == 0) qbk[b] = p;
        }
    }
}

// Reduce DSPLIT partials -> qk[b,0:768], lint[b,0:512] (deterministic order).
__global__ __launch_bounds__(256) void k_qkr(const float* __restrict__ pws,
        float* __restrict__ qk, float* __restrict__ lint) {
    int idx = blockIdx.x * 256 + threadIdx.x;   // 0 .. 10239
    if (idx >= BB * ETOT) return;
    int b = idx / ETOT, e = idx % ETOT;
    float acc = 0.f;
    #pragma unroll
    for (int ds = 0; ds < DSPLIT; ++ds)
        acc += pws[((size_t)ds * BB + b) * ETOT + e];
    if (e < DD) qk[b * DD + e] = acc;
    else lint[b * NPOS + (e - DD)] = acc;
}

// logits[b,t] = scale * (x[b,t,:].qk[b,:] + qbk[b]); masked -> -inf. Wave per
// row, 4096 blocks (R3-proven streaming shape).
__global__ __launch_bounds__(256) void k_logits(const float* __restrict__ x,
        const float* __restrict__ qk, const float* __restrict__ qbk,
        const int* __restrict__ mask, float* __restrict__ logits) {
    int gw = (blockIdx.x * 256 + threadIdx.x) >> 6;
    int lane = threadIdx.x & 63;
    if (gw >= BB * SS) return;
    int b = gw >> 11;
    const float4* xr = (const float4*)(x + (size_t)gw * DD);
    const float4* wr = (const float4*)(qk + (size_t)b * DD);
    float acc = 0.f;
    #pragma unroll
    for (int j = 0; j < 3; ++j) {
        float4 a = xr[lane + 64 * j];
        float4 w = wr[lane + 64 * j];
        acc += a.x * w.x + a.y * w.y + a.z * w.z + a.w * w.w;
    }
    acc = wave_sum(acc);
    if (lane == 0) {
        float lg = (acc + qbk[b]) * SCALE;
        logits[gw] = mask[gw] ? lg : -INFINITY;
    }
}

// Fused scan + ctx: grid (TC, BB) = (64, 8), 256 thr (R9-proven). Each block
// runs the deterministic scan (identical attn everywhere), then accumulates
// its 32-row x chunk into ctx (atomic, linear-safe).
__global__ __launch_bounds__(256) void k_ctxscan(const float* __restrict__ x,
        const float* __restrict__ logits, const float* __restrict__ lint,
        float* __restrict__ ctx) {
    const int tc = blockIdx.x, b = blockIdx.y, tid = threadIdx.x;
    __shared__ float lg[SS];
    __shared__ float li[NPOS];
    __shared__ float sa[256], sb[256];
    for (int i = tid; i < SS; i += 256) lg[i] = logits[b * SS + i];
    for (int i = tid; i < NPOS; i += 256) li[i] = lint[b * NPOS + i];
    __syncthreads();
    int base = tid * 8;
    float loc[8];
    float run = 0.f;
    #pragma unroll
    for (int k = 7; k >= 0; --k) {          // suffix sum within own chunk
        float v = lg[base + k];
        float gk = 1.f / (1.f + expf(-v));  // sigmoid; -inf -> 0
        run += gk;
        loc[k] = run;
    }
    sa[tid] = run;
    __syncthreads();
    // Hillis-Steele inclusive SUFFIX scan over 256 chunk totals (ping-pong)
    float* src = sa; float* dst = sb;
    for (int off = 1; off < 256; off <<= 1) {
        float v = src[tid];
        if (tid + off < 256) v += src[tid + off];
        dst[tid] = v;
        __syncthreads();
        float* t_ = src; src = dst; dst = t_;
    }
    float st = (tid < 255) ? src[tid + 1] : 0.f;
    float adj[8];
    float m = -INFINITY;
    #pragma unroll
    for (int k = 0; k < 8; ++k) {
        float val = lg[base + k];
        float nv;
        if (val == -INFINITY) {
            nv = val;
        } else {
            float p = fminf(loc[k] + st, (float)(NPOS - 1));
            float pf = floorf(p);
            float wt = p - pf;
            int fi = (int)pf;
            int ci = (int)ceilf(p);
            nv = val + li[ci] * wt + li[fi] * (1.f - wt);
        }
        adj[k] = nv;
        m = fmaxf(m, nv);
    }
    __syncthreads();            // scan LDS reads done; safe to reuse sa/sb
    sa[tid] = m;
    __syncthreads();
    for (int s2 = 128; s2 > 0; s2 >>= 1) {
        if (tid < s2) sa[tid] = fmaxf(sa[tid], sa[tid + s2]);
        __syncthreads();
    }
    float bm = sa[0];
    __syncthreads();
    float sum = 0.f;
    #pragma unroll
    for (int k = 0; k < 8; ++k) { adj[k] = expf(adj[k] - bm); sum += adj[k]; }
    sa[tid] = sum;
    __syncthreads();
    for (int s2 = 128; s2 > 0; s2 >>= 1) {
        if (tid < s2) sa[tid] += sa[tid + s2];
        __syncthreads();
    }
    float inv = 1.f / sa[0];
    #pragma unroll
    for (int k = 0; k < 8; ++k) lg[base + k] = adj[k] * inv;   // attn into lg
    __syncthreads();
    // weighted x-row sum for this block's 32-row chunk
    if (tid < 192) {
        const int TPC = SS / TC;  // 32
        float4 acc = make_float4(0.f, 0.f, 0.f, 0.f);
        const float4* xr = (const float4*)(x + ((size_t)b * SS + (size_t)tc * TPC) * DD);
        const float* at = lg + tc * TPC;
        for (int i = 0; i < TPC; ++i) {
            float a = at[i];
            float4 xv = xr[(size_t)i * 192 + tid];
            acc.x += a * xv.x; acc.y += a * xv.y; acc.z += a * xv.z; acc.w += a * xv.w;
        }
        float* dstp = ctx + b * DD + tid * 4;
        atomicAdd(dstp + 0, acc.x);
        atomicAdd(dstp + 1, acc.y);
        atomicAdd(dstp + 2, acc.z);
        atomicAdd(dstp + 3, acc.w);
    }
}

// out[b,d] = ctx[b,:].Wv[d,:] + bv[d]; wave per output.
__global__ __launch_bounds__(256) void k_out(const float* __restrict__ ctx,
        const float* __restrict__ Wv, const float* __restrict__ bv,
        float* __restrict__ out) {
    int gw = (blockIdx.x * 256 + threadIdx.x) >> 6;
    int lane = threadIdx.x & 63;
    if (gw >= BB * DD) return;
    int b = gw / DD, d = gw % DD;
    const float4* vr = (const float4*)(ctx + (size_t)b * DD);
    const float4* wr = (const float4*)(Wv + (size_t)d * DD);
    float acc = 0.f;
    #pragma unroll
    for (int j = 0; j < 3; ++j) {
        float4 a = vr[lane + 64 * j];
        float4 w = wr[lane + 64 * j];
        acc += a.x * w.x + a.y * w.y + a.z * w.z + a.w * w.w;
    }
    acc = wave_sum(acc);
    if (lane == 0) out[gw] = acc + bv[d];
}

extern "C" void kernel_launch(void* const* d_in, const int* in_sizes, int n_in,
                              void* d_out, int out_size, void* d_ws, size_t ws_size,
                              hipStream_t stream) {
    const float* x       = (const float*)d_in[0];  // [B,S,D]
    const int*   mask    = (const int*)  d_in[1];  // [B,S]
    const float* Wq      = (const float*)d_in[2];
    const float* bq      = (const float*)d_in[3];
    const float* Wk      = (const float*)d_in[4];
    const float* bk      = (const float*)d_in[5];
    const float* Wv      = (const float*)d_in[6];
    const float* bv      = (const float*)d_in[7];
    const float* pos_emb = (const float*)d_in[8];  // [D,NPOS]
    float* out = (float*)d_out;                    // [B,D]
    float* ws  = (float*)d_ws;

    float* logits = ws + WS_LOGITS;
    float* ctx    = ws + WS_CTX;
    float* q      = ws + WS_Q;
    float* qk     = ws + WS_QK;
    float* lint   = ws + WS_LI;
    float* qbk    = ws + WS_QBK;
    float* pws    = ws + WS_PWS;

    // 1. q from row s=0 (wave per output, 1536 blocks); zero ctx
    k_q<<<dim3((BB * DD) / 4), dim3(256), 0, stream>>>(x, Wq, bq, q, ctx);
    // 2. q @ [Wk | pos_emb] -> deterministic partials; qbk
    k_qkw<<<dim3(5, DSPLIT), dim3(256), 0, stream>>>(q, Wk, bk, pos_emb, pws, qbk);
    // 3. tiny deterministic reduce -> qk, lint
    k_qkr<<<dim3(40), dim3(256), 0, stream>>>(pws, qk, lint);
    // 4. logits (pass 1 over x, 50 MB; 4096 blocks, wave per row)
    k_logits<<<dim3((BB * SS) / 4), dim3(256), 0, stream>>>(x, qk, qbk, mask, logits);
    // 5. fused scan + ctx (pass 2 over x; 512 blocks)
    k_ctxscan<<<dim3(TC, BB), dim3(256), 0, stream>>>(x, logits, lint, ctx);
    // 6. out = ctx @ Wv.T + bv
    k_out<<<dim3((BB * DD) / 4), dim3(256), 0, stream>>>(ctx, Wv, bv, out);
}